// Round 17
// baseline (124.820 us; speedup 1.0000x reference)
//
#include <hip/hip_runtime.h>

#define B_ 2
#define S_ 1024
#define D_ 2048
#define H_ 32
#define KV_ 4
#define HD_ 64
#define NQKV 2560  // H*HD + KV*HD + KV*HD
#define KVB 64     // attention KV chunk

typedef __attribute__((ext_vector_type(8))) short bf16x8;
typedef __attribute__((ext_vector_type(4))) float f32x4;
typedef __attribute__((ext_vector_type(16))) float f32x16;

__device__ __forceinline__ unsigned short f2bf(float f) {
  unsigned int u = __float_as_uint(f);
  u = (u + 0x7fffu + ((u >> 16) & 1u)) >> 16;   // RNE
  return (unsigned short)u;
}
__device__ __forceinline__ unsigned int cvt_pk_bf16(float a, float b) {
  unsigned int r;
  asm("v_cvt_pk_bf16_f32 %0, %1, %2" : "=v"(r) : "v"(a), "v"(b));
  return r;
}
__device__ __forceinline__ float exp2f_fast(float x) {
  return __builtin_amdgcn_exp2f(x);   // bare v_exp_f32
}

#define GLOAD_LDS(gp, lp) \
  __builtin_amdgcn_global_load_lds((const __attribute__((address_space(1))) void*)(gp), \
                                   (__attribute__((address_space(3))) void*)(lp), 16, 0, 0)

// ---------------- elementwise f32 -> bf16 ----------------
__global__ __launch_bounds__(256) void k_convert(const float* __restrict__ src,
                                                 unsigned short* __restrict__ dst, int n4) {
  int i = blockIdx.x * 256 + threadIdx.x;
  if (i >= n4) return;
  float4 v = ((const float4*)src)[i];
  ushort4 o;
  o.x = f2bf(v.x); o.y = f2bf(v.y); o.z = f2bf(v.z); o.w = f2bf(v.w);
  ((ushort4*)dst)[i] = o;
}

// ---------------- merged weight transposes: f32 (K x N) -> bf16 (N x K) ----------------
__global__ __launch_bounds__(256) void k_transpose4(const float* __restrict__ wq,
                                                    const float* __restrict__ wk,
                                                    const float* __restrict__ wv,
                                                    const float* __restrict__ wo,
                                                    unsigned short* __restrict__ wft,
                                                    unsigned short* __restrict__ wot) {
  __shared__ float tile[32][33];
  const int z = blockIdx.z;
  const float* src;
  unsigned short* dst;
  int N, roff;
  if (z == 0)      { src = wq; dst = wft; N = 2048; roff = 0; }
  else if (z == 1) { src = wk; dst = wft; N = 256;  roff = 2048; }
  else if (z == 2) { src = wv; dst = wft; N = 256;  roff = 2304; }
  else             { src = wo; dst = wot; N = 2048; roff = 0; }
  int n0 = blockIdx.x * 32, k0 = blockIdx.y * 32;
  if (n0 >= N) return;
  int tx = threadIdx.x & 31, ty = threadIdx.x >> 5;
  #pragma unroll
  for (int i = 0; i < 4; ++i)
    tile[ty + 8 * i][tx] = src[(size_t)(k0 + ty + 8 * i) * N + (n0 + tx)];
  __syncthreads();
  #pragma unroll
  for (int i = 0; i < 4; ++i)
    dst[(size_t)(roff + n0 + ty + 8 * i) * D_ + (k0 + tx)] = f2bf(tile[tx][ty + 8 * i]);
}

// ---------------- GEMM: C[M][N] = A[M][K] * Bt[N][K]^T, bf16 in ----------------
// 128x128 tile (F/B = 64 vs 42.7 at 64x128 -> 1/3 less staged traffic at the
// ~13 TB/s chip-wide staging ceiling), BK=64, 4 waves (2x2 of 64x64),
// DOUBLE-BUFFERED (needed: grid gives only 1-1.25 blocks/CU), LDS XOR-swizzled.
// MODE 0: plain f32 C write. MODE 1: fused QKV epilogue (RoPE; q pre-scaled by
// log2(e)/sqrt(HD); V transposed to (B,KV,HD,S)). MODE 1 requires BN/2 == 64.
template <int BM, int BN, int MODE>
__global__ __launch_bounds__(256) void k_gemm(const unsigned short* __restrict__ A,
                                              const unsigned short* __restrict__ Bt,
                                              float* __restrict__ C,
                                              const float* __restrict__ cosT,
                                              const float* __restrict__ sinT,
                                              const int* __restrict__ posp,
                                              unsigned short* __restrict__ q_r,
                                              unsigned short* __restrict__ k_r,
                                              unsigned short* __restrict__ v_t,
                                              int M, int N, int K) {
  constexpr int MR = BM / 32;
  constexpr int NR = BN / 32;
  __shared__ alignas(16) unsigned short As[2][BM * 64];
  __shared__ alignas(16) unsigned short Bs[2][BN * 64];
  const int tid = threadIdx.x;
  const int wid = tid >> 6, lane = tid & 63;
  const int lo = lane & 15, hi = lane >> 4;
  const int m0 = blockIdx.y * BM, n0 = blockIdx.x * BN;
  const int wr = wid >> 1, wc = wid & 1;
  f32x4 acc[MR][NR] = {};

  auto stage = [&](int kt, int bi) {
    #pragma unroll
    for (int u = tid; u < BM * 8; u += 256) {
      int row = u >> 3, ch = u & 7, chs = ch ^ (row & 7);
      GLOAD_LDS(A + (size_t)(m0 + row) * K + kt * 64 + chs * 8, &As[bi][u * 8]);
    }
    #pragma unroll
    for (int u = tid; u < BN * 8; u += 256) {
      int row = u >> 3, ch = u & 7, chs = ch ^ (row & 7);
      GLOAD_LDS(Bt + (size_t)(n0 + row) * K + kt * 64 + chs * 8, &Bs[bi][u * 8]);
    }
  };

  const int nkt = K >> 6;
  int buf = 0;
  stage(0, 0);
  __syncthreads();

  for (int kt = 0; kt < nkt; ++kt) {
    if (kt + 1 < nkt) stage(kt + 1, buf ^ 1);   // prefetch streams during compute
    #pragma unroll
    for (int ks = 0; ks < 2; ++ks) {
      const int chs = (ks * 4 + hi) ^ (lo & 7);
      bf16x8 a[MR], b[NR];
      #pragma unroll
      for (int m = 0; m < MR; ++m) {
        int row = wr * (BM / 2) + m * 16 + lo;
        a[m] = *(const bf16x8*)(&As[buf][row * 64 + chs * 8]);
      }
      #pragma unroll
      for (int n = 0; n < NR; ++n) {
        int row = wc * (BN / 2) + n * 16 + lo;
        b[n] = *(const bf16x8*)(&Bs[buf][row * 64 + chs * 8]);
      }
      __builtin_amdgcn_s_setprio(1);
      #pragma unroll
      for (int m = 0; m < MR; ++m)
        #pragma unroll
        for (int n = 0; n < NR; ++n)
          acc[m][n] = __builtin_amdgcn_mfma_f32_16x16x32_bf16(a[m], b[n], acc[m][n], 0, 0, 0);
      __builtin_amdgcn_s_setprio(0);
    }
    __syncthreads();
    buf ^= 1;
  }

  if (MODE == 0) {
    const int cr = hi * 4;
    #pragma unroll
    for (int m = 0; m < MR; ++m)
      #pragma unroll
      for (int n = 0; n < NR; ++n) {
        int col = n0 + wc * (BN / 2) + n * 16 + lo;
        int rowb = m0 + wr * (BM / 2) + m * 16 + cr;
        #pragma unroll
        for (int r = 0; r < 4; ++r)
          C[(size_t)(rowb + r) * N + col] = acc[m][n][r];
      }
  } else {
    const int col0 = n0 + wc * (BN / 2);
    const int pos = posp[0];
    const float qsc = 0.125f * 1.44269504f;   // 1/sqrt(HD) * log2(e)
    if (col0 < 2048) {            // ---- Q + RoPE, pre-scaled ----
      const int h = col0 >> 6;
      #pragma unroll
      for (int m = 0; m < MR; ++m)
        #pragma unroll
        for (int r = 0; r < 4; ++r) {
          int row = m0 + wr * (BM / 2) + m * 16 + hi * 4 + r;
          int s = row & (S_ - 1), b = row >> 10;
          unsigned short* base = q_r + ((size_t)(b * H_ + h) * S_ + s) * HD_;
          #pragma unroll
          for (int np = 0; np < 2; ++np) {
            int i = np * 16 + lo;
            float t1 = acc[m][np][r], t2 = acc[m][np + 2][r];
            float c = cosT[(size_t)(pos + s) * 32 + i];
            float sn = sinT[(size_t)(pos + s) * 32 + i];
            base[i] = f2bf((t1 * c - t2 * sn) * qsc);
            base[i + 32] = f2bf((t2 * c + t1 * sn) * qsc);
          }
        }
    } else if (col0 < 2304) {     // ---- K + RoPE ----
      const int g = (col0 - 2048) >> 6;
      #pragma unroll
      for (int m = 0; m < MR; ++m)
        #pragma unroll
        for (int r = 0; r < 4; ++r) {
          int row = m0 + wr * (BM / 2) + m * 16 + hi * 4 + r;
          int s = row & (S_ - 1), b = row >> 10;
          unsigned short* base = k_r + ((size_t)(b * KV_ + g) * S_ + s) * HD_;
          #pragma unroll
          for (int np = 0; np < 2; ++np) {
            int i = np * 16 + lo;
            float t1 = acc[m][np][r], t2 = acc[m][np + 2][r];
            float c = cosT[(size_t)(pos + s) * 32 + i];
            float sn = sinT[(size_t)(pos + s) * 32 + i];
            base[i] = f2bf(t1 * c - t2 * sn);
            base[i + 32] = f2bf(t2 * c + t1 * sn);
          }
        }
    } else {                      // ---- V -> (B,KV,HD,S) transposed bf16 ----
      const int g = (col0 - 2304) >> 6;
      #pragma unroll
      for (int m = 0; m < MR; ++m) {
        int row0 = m0 + wr * (BM / 2) + m * 16 + hi * 4;
        int s0 = row0 & (S_ - 1), b = row0 >> 10;
        #pragma unroll
        for (int n = 0; n < NR; ++n) {
          int d = n * 16 + lo;
          ushort4 o;
          o.x = f2bf(acc[m][n][0]);
          o.y = f2bf(acc[m][n][1]);
          o.z = f2bf(acc[m][n][2]);
          o.w = f2bf(acc[m][n][3]);
          *(ushort4*)(v_t + ((size_t)(b * KV_ + g) * HD_ + d) * S_ + s0) = o;
        }
      }
    }
  }
}

// ---------------- MFMA flash attention, 32x32 swapped-QK^T, log2-domain softmax ------------
// grid (64 bh, 16 qt); heavy-first (qt = 15 - blockIdx.y). 2 waves x 32 q = 64 q/block.
// (R13 version — paired-chunk variant regressed, reverted.)
__global__ __launch_bounds__(128) void k_attn(const unsigned short* __restrict__ qr,
                                              const unsigned short* __restrict__ kr,
                                              const unsigned short* __restrict__ vt,
                                              unsigned short* __restrict__ ao) {
  __shared__ alignas(16) unsigned short k_lds[2 * KVB * HD_];   // [buf][j][d], chunk-XOR-swz
  __shared__ alignas(16) unsigned short v_lds[2 * HD_ * KVB];   // [buf][d][j], chunk-XOR-swz
  const int tid = threadIdx.x;
  const int wid = tid >> 6, lane = tid & 63;
  const int l31 = lane & 31, hi5 = lane >> 5;
  const int bh = blockIdx.x;
  const int h = bh >> 1, b = bh & 1, g = h >> 3;
  const int qt = 15 - (int)blockIdx.y;            // heavy-first dispatch
  const int nch = qt + 1;
  const int q_abs = qt * 64 + wid * 32 + l31;

  const unsigned short* qrow = qr + ((size_t)(b * H_ + h) * S_ + q_abs) * HD_;
  bf16x8 qf[4];
  #pragma unroll
  for (int ks = 0; ks < 4; ++ks)
    qf[ks] = *(const bf16x8*)(qrow + ks * 16 + hi5 * 8);

  const unsigned short* kbase = kr + (size_t)(b * KV_ + g) * S_ * HD_;
  const unsigned short* vbase = vt + (size_t)(b * KV_ + g) * HD_ * S_;

  const unsigned short* kg[4];
  const unsigned short* vg[4];
  int ldo[4];
  #pragma unroll
  for (int ii = 0; ii < 4; ++ii) {
    int uu = ii * 128 + tid;               // 16B unit, 0..511
    int r = uu >> 3, ch = uu & 7, chs = ch ^ (r & 7);
    kg[ii] = kbase + r * HD_ + chs * 8;
    vg[ii] = vbase + (size_t)r * S_ + chs * 8;
    ldo[ii] = uu * 8;
  }
  int chs8[4];
  #pragma unroll
  for (int ks = 0; ks < 4; ++ks) chs8[ks] = ((ks * 2 + hi5) ^ (l31 & 7)) * 8;
  const int krow = l31 * 64;

  f32x16 oacc[2] = {};   // O^T: col q=l31, row d=(r&3)+8*(r>>2)+4*hi5+32*dt
  float mrun = -1e30f, ls = 0.f;
  int buf = 0;

  auto stage = [&](int c, int bi) {
    #pragma unroll
    for (int ii = 0; ii < 4; ++ii)
      GLOAD_LDS(kg[ii] + (size_t)c * (KVB * HD_), k_lds + bi * 4096 + ldo[ii]);
    #pragma unroll
    for (int ii = 0; ii < 4; ++ii)
      GLOAD_LDS(vg[ii] + (size_t)c * KVB, v_lds + bi * 4096 + ldo[ii]);
  };

  stage(0, 0);
  __syncthreads();

  for (int c = 0; c < nch; ++c) {
    if (c + 1 < nch) stage(c + 1, buf ^ 1);
    const unsigned short* kl = k_lds + buf * 4096;
    const unsigned short* vl = v_lds + buf * 4096;
    const int j0 = c * KVB;

    // S^T tiles (32j x 32q): A = K rows, B = Q
    f32x16 st[2] = {};
    __builtin_amdgcn_s_setprio(1);
    #pragma unroll
    for (int ks = 0; ks < 4; ++ks)
      #pragma unroll
      for (int jt = 0; jt < 2; ++jt) {
        bf16x8 kf = *(const bf16x8*)(kl + jt * 2048 + krow + chs8[ks]);
        st[jt] = __builtin_amdgcn_mfma_f32_32x32x16_bf16(kf, qf[ks], st[jt], 0, 0, 0);
      }
    __builtin_amdgcn_s_setprio(0);

    // causal mask (diagonal chunk only) + row max
    float pmax = -1e30f;
    if (c == nch - 1) {
      #pragma unroll
      for (int jt = 0; jt < 2; ++jt)
        #pragma unroll
        for (int r = 0; r < 16; ++r) {
          int j_abs = j0 + jt * 32 + (r & 3) + 8 * (r >> 2) + 4 * hi5;
          if (j_abs > q_abs) st[jt][r] = -1e30f;
          pmax = fmaxf(pmax, st[jt][r]);
        }
    } else {
      #pragma unroll
      for (int jt = 0; jt < 2; ++jt)
        #pragma unroll
        for (int r = 0; r < 16; ++r) pmax = fmaxf(pmax, st[jt][r]);
    }
    pmax = fmaxf(pmax, __shfl_xor(pmax, 32, 64));   // lane pair shares q

    // defer-max: rescale only when some lane's max rose (wave-uniform branch)
    if (__any(pmax > mrun)) {
      float mn = fmaxf(mrun, pmax);
      float scale = exp2f_fast(mrun - mn);
      ls *= scale;
      #pragma unroll
      for (int dt = 0; dt < 2; ++dt)
        #pragma unroll
        for (int r = 0; r < 16; ++r) oacc[dt][r] *= scale;
      mrun = mn;
    }
    float ls0 = 0.f, ls1 = 0.f, ls2 = 0.f, ls3 = 0.f;
    #pragma unroll
    for (int jt = 0; jt < 2; ++jt)
      #pragma unroll
      for (int r = 0; r < 16; ++r) {
        float e = exp2f_fast(st[jt][r] - mrun);   // log2-domain: bare v_exp_f32
        st[jt][r] = e;
        if ((r & 3) == 0) ls0 += e; else if ((r & 3) == 1) ls1 += e;
        else if ((r & 3) == 2) ls2 += e; else ls3 += e;
      }
    ls += (ls0 + ls1) + (ls2 + ls3);

    // pack P to bf16 quads via v_cvt_pk_bf16_f32 (pk[jt][quad] = rows {4q..4q+3})
    unsigned int pk[2][4][2];
    #pragma unroll
    for (int jt = 0; jt < 2; ++jt)
      #pragma unroll
      for (int qd = 0; qd < 4; ++qd) {
        pk[jt][qd][0] = cvt_pk_bf16(st[jt][qd * 4 + 0], st[jt][qd * 4 + 1]);
        pk[jt][qd][1] = cvt_pk_bf16(st[jt][qd * 4 + 2], st[jt][qd * 4 + 3]);
      }

    // redistribute across lane^32 into PV B-fragments (k=j, col=q)
    bf16x8 pf[4];
    #pragma unroll
    for (int jt = 0; jt < 2; ++jt) {
      unsigned int ex0a = hi5 ? pk[jt][0][0] : pk[jt][1][0];
      unsigned int ex0b = hi5 ? pk[jt][0][1] : pk[jt][1][1];
      unsigned int ex1a = hi5 ? pk[jt][2][0] : pk[jt][3][0];
      unsigned int ex1b = hi5 ? pk[jt][2][1] : pk[jt][3][1];
      unsigned int rA0 = (unsigned int)__shfl_xor((int)ex0a, 32, 64);
      unsigned int rA1 = (unsigned int)__shfl_xor((int)ex0b, 32, 64);
      unsigned int rB0 = (unsigned int)__shfl_xor((int)ex1a, 32, 64);
      unsigned int rB1 = (unsigned int)__shfl_xor((int)ex1b, 32, 64);
      union { unsigned int w[4]; bf16x8 v; } fe, fo;
      if (hi5) {
        fe.w[0] = rA0; fe.w[1] = rA1; fe.w[2] = pk[jt][1][0]; fe.w[3] = pk[jt][1][1];
        fo.w[0] = rB0; fo.w[1] = rB1; fo.w[2] = pk[jt][3][0]; fo.w[3] = pk[jt][3][1];
      } else {
        fe.w[0] = pk[jt][0][0]; fe.w[1] = pk[jt][0][1]; fe.w[2] = rA0; fe.w[3] = rA1;
        fo.w[0] = pk[jt][2][0]; fo.w[1] = pk[jt][2][1]; fo.w[2] = rB0; fo.w[3] = rB1;
      }
      pf[jt * 2 + 0] = fe.v;
      pf[jt * 2 + 1] = fo.v;
    }

    // O^T += Vt · P^T
    __builtin_amdgcn_s_setprio(1);
    #pragma unroll
    for (int ks = 0; ks < 4; ++ks)
      #pragma unroll
      for (int dt = 0; dt < 2; ++dt) {
        bf16x8 vf = *(const bf16x8*)(vl + dt * 2048 + krow + chs8[ks]);
        oacc[dt] = __builtin_amdgcn_mfma_f32_32x32x16_bf16(vf, pf[ks], oacc[dt], 0, 0, 0);
      }
    __builtin_amdgcn_s_setprio(0);

    __syncthreads();   // prefetch landed; all waves done with buf
    buf ^= 1;
  }

  float tot = ls + __shfl_xor(ls, 32, 64);
  float inv = 1.f / tot;
  unsigned short* orow = ao + (size_t)(b * S_ + q_abs) * (H_ * HD_) + h * HD_;
  #pragma unroll
  for (int dt = 0; dt < 2; ++dt)
    #pragma unroll
    for (int rg = 0; rg < 4; ++rg) {
      uint2 w;
      w.x = cvt_pk_bf16(oacc[dt][rg * 4 + 0] * inv, oacc[dt][rg * 4 + 1] * inv);
      w.y = cvt_pk_bf16(oacc[dt][rg * 4 + 2] * inv, oacc[dt][rg * 4 + 3] * inv);
      *(uint2*)(orow + dt * 32 + rg * 8 + hi5 * 4) = w;
    }
}

extern "C" void kernel_launch(void* const* d_in, const int* in_sizes, int n_in,
                              void* d_out, int out_size, void* d_ws, size_t ws_size,
                              hipStream_t stream) {
  const float* x    = (const float*)d_in[0];
  const float* wq   = (const float*)d_in[1];
  const float* wk   = (const float*)d_in[2];
  const float* wv   = (const float*)d_in[3];
  const float* wo   = (const float*)d_in[4];
  const float* cosT = (const float*)d_in[5];
  const float* sinT = (const float*)d_in[6];
  const int*   posp = (const int*)d_in[8];
  float* out = (float*)d_out;

  char* ws = (char*)d_ws;
  size_t off = 0;
  auto alloc = [&](size_t bytes) {
    char* p = ws + off;
    off += (bytes + 255) & ~(size_t)255;
    return p;
  };
  unsigned short* xb  = (unsigned short*)alloc((size_t)B_ * S_ * D_ * 2);
  unsigned short* wft = (unsigned short*)alloc((size_t)NQKV * D_ * 2);
  unsigned short* wot = (unsigned short*)alloc((size_t)D_ * D_ * 2);
  unsigned short* q_r = (unsigned short*)alloc((size_t)B_ * H_ * S_ * HD_ * 2);
  unsigned short* k_r = (unsigned short*)alloc((size_t)B_ * KV_ * S_ * HD_ * 2);
  unsigned short* v_t = (unsigned short*)alloc((size_t)B_ * KV_ * HD_ * S_ * 2);
  unsigned short* ao  = (unsigned short*)alloc((size_t)B_ * S_ * H_ * HD_ * 2);
  if (off > ws_size) return;

  k_convert<<<(B_ * S_ * D_ / 4 + 255) / 256, 256, 0, stream>>>(x, xb, B_ * S_ * D_ / 4);
  k_transpose4<<<dim3(D_ / 32, D_ / 32, 4), 256, 0, stream>>>(wq, wk, wv, wo, wft, wot);

  // QKV GEMM: 128x128 dbuf tiles (320 blocks) with fused RoPE / V-transpose epilogue
  k_gemm<128, 128, 1><<<dim3(NQKV / 128, (B_ * S_) / 128), 256, 0, stream>>>(
      xb, wft, nullptr, cosT, sinT, posp, q_r, k_r, v_t, B_ * S_, NQKV, D_);

  // 32x32 swapped-QK^T attention, heavy-first uniform blocks (2 waves, 64 q each)
  k_attn<<<dim3(64, 16), 128, 0, stream>>>(q_r, k_r, v_t, ao);

  // Output GEMM: 128x128 dbuf tiles (256 blocks)
  k_gemm<128, 128, 0><<<dim3(D_ / 128, (B_ * S_) / 128), 256, 0, stream>>>(
      ao, wot, out, nullptr, nullptr, nullptr, nullptr, nullptr, nullptr, B_ * S_, D_, D_);
}

// Round 18
// 124.416 us; speedup vs baseline: 1.0032x; 1.0032x over previous
//
#include <hip/hip_runtime.h>

#define B_ 2
#define S_ 1024
#define D_ 2048
#define H_ 32
#define KV_ 4
#define HD_ 64
#define NQKV 2560  // H*HD + KV*HD + KV*HD
#define KVB 64     // attention KV chunk

typedef __attribute__((ext_vector_type(8))) short bf16x8;
typedef __attribute__((ext_vector_type(4))) float f32x4;
typedef __attribute__((ext_vector_type(16))) float f32x16;

__device__ __forceinline__ unsigned short f2bf(float f) {
  unsigned int u = __float_as_uint(f);
  u = (u + 0x7fffu + ((u >> 16) & 1u)) >> 16;   // RNE
  return (unsigned short)u;
}
__device__ __forceinline__ unsigned int cvt_pk_bf16(float a, float b) {
  unsigned int r;
  asm("v_cvt_pk_bf16_f32 %0, %1, %2" : "=v"(r) : "v"(a), "v"(b));
  return r;
}
__device__ __forceinline__ float exp2f_fast(float x) {
  return __builtin_amdgcn_exp2f(x);   // bare v_exp_f32
}

#define GLOAD_LDS(gp, lp) \
  __builtin_amdgcn_global_load_lds((const __attribute__((address_space(1))) void*)(gp), \
                                   (__attribute__((address_space(3))) void*)(lp), 16, 0, 0)

// ---------------- elementwise f32 -> bf16 ----------------
__global__ __launch_bounds__(256) void k_convert(const float* __restrict__ src,
                                                 unsigned short* __restrict__ dst, int n4) {
  int i = blockIdx.x * 256 + threadIdx.x;
  if (i >= n4) return;
  float4 v = ((const float4*)src)[i];
  ushort4 o;
  o.x = f2bf(v.x); o.y = f2bf(v.y); o.z = f2bf(v.z); o.w = f2bf(v.w);
  ((ushort4*)dst)[i] = o;
}

// ---------------- merged weight transposes: f32 (K x N) -> bf16 (N x K) ----------------
__global__ __launch_bounds__(256) void k_transpose4(const float* __restrict__ wq,
                                                    const float* __restrict__ wk,
                                                    const float* __restrict__ wv,
                                                    const float* __restrict__ wo,
                                                    unsigned short* __restrict__ wft,
                                                    unsigned short* __restrict__ wot) {
  __shared__ float tile[32][33];
  const int z = blockIdx.z;
  const float* src;
  unsigned short* dst;
  int N, roff;
  if (z == 0)      { src = wq; dst = wft; N = 2048; roff = 0; }
  else if (z == 1) { src = wk; dst = wft; N = 256;  roff = 2048; }
  else if (z == 2) { src = wv; dst = wft; N = 256;  roff = 2304; }
  else             { src = wo; dst = wot; N = 2048; roff = 0; }
  int n0 = blockIdx.x * 32, k0 = blockIdx.y * 32;
  if (n0 >= N) return;
  int tx = threadIdx.x & 31, ty = threadIdx.x >> 5;
  #pragma unroll
  for (int i = 0; i < 4; ++i)
    tile[ty + 8 * i][tx] = src[(size_t)(k0 + ty + 8 * i) * N + (n0 + tx)];
  __syncthreads();
  #pragma unroll
  for (int i = 0; i < 4; ++i)
    dst[(size_t)(roff + n0 + ty + 8 * i) * D_ + (k0 + tx)] = f2bf(tile[tx][ty + 8 * i]);
}

// ---------------- GEMM: C[M][N] = A[M][K] * Bt[N][K]^T, bf16 in ----------------
// 128x128 tile (F/B = 64 vs 42.7 at 64x128 -> 1/3 less staged traffic at the
// ~13 TB/s chip-wide staging ceiling), BK=64, 4 waves (2x2 of 64x64),
// DOUBLE-BUFFERED (needed: grid gives only 1-1.25 blocks/CU), LDS XOR-swizzled.
// MODE 0: plain f32 C write. MODE 1: fused QKV epilogue (RoPE; q pre-scaled by
// log2(e)/sqrt(HD); V transposed to (B,KV,HD,S)). MODE 1 requires BN/2 == 64.
template <int BM, int BN, int MODE>
__global__ __launch_bounds__(256) void k_gemm(const unsigned short* __restrict__ A,
                                              const unsigned short* __restrict__ Bt,
                                              float* __restrict__ C,
                                              const float* __restrict__ cosT,
                                              const float* __restrict__ sinT,
                                              const int* __restrict__ posp,
                                              unsigned short* __restrict__ q_r,
                                              unsigned short* __restrict__ k_r,
                                              unsigned short* __restrict__ v_t,
                                              int M, int N, int K) {
  constexpr int MR = BM / 32;
  constexpr int NR = BN / 32;
  __shared__ alignas(16) unsigned short As[2][BM * 64];
  __shared__ alignas(16) unsigned short Bs[2][BN * 64];
  const int tid = threadIdx.x;
  const int wid = tid >> 6, lane = tid & 63;
  const int lo = lane & 15, hi = lane >> 4;
  const int m0 = blockIdx.y * BM, n0 = blockIdx.x * BN;
  const int wr = wid >> 1, wc = wid & 1;
  f32x4 acc[MR][NR] = {};

  auto stage = [&](int kt, int bi) {
    #pragma unroll
    for (int u = tid; u < BM * 8; u += 256) {
      int row = u >> 3, ch = u & 7, chs = ch ^ (row & 7);
      GLOAD_LDS(A + (size_t)(m0 + row) * K + kt * 64 + chs * 8, &As[bi][u * 8]);
    }
    #pragma unroll
    for (int u = tid; u < BN * 8; u += 256) {
      int row = u >> 3, ch = u & 7, chs = ch ^ (row & 7);
      GLOAD_LDS(Bt + (size_t)(n0 + row) * K + kt * 64 + chs * 8, &Bs[bi][u * 8]);
    }
  };

  const int nkt = K >> 6;
  int buf = 0;
  stage(0, 0);
  __syncthreads();

  for (int kt = 0; kt < nkt; ++kt) {
    if (kt + 1 < nkt) stage(kt + 1, buf ^ 1);   // prefetch streams during compute
    #pragma unroll
    for (int ks = 0; ks < 2; ++ks) {
      const int chs = (ks * 4 + hi) ^ (lo & 7);
      bf16x8 a[MR], b[NR];
      #pragma unroll
      for (int m = 0; m < MR; ++m) {
        int row = wr * (BM / 2) + m * 16 + lo;
        a[m] = *(const bf16x8*)(&As[buf][row * 64 + chs * 8]);
      }
      #pragma unroll
      for (int n = 0; n < NR; ++n) {
        int row = wc * (BN / 2) + n * 16 + lo;
        b[n] = *(const bf16x8*)(&Bs[buf][row * 64 + chs * 8]);
      }
      __builtin_amdgcn_s_setprio(1);
      #pragma unroll
      for (int m = 0; m < MR; ++m)
        #pragma unroll
        for (int n = 0; n < NR; ++n)
          acc[m][n] = __builtin_amdgcn_mfma_f32_16x16x32_bf16(a[m], b[n], acc[m][n], 0, 0, 0);
      __builtin_amdgcn_s_setprio(0);
    }
    __syncthreads();
    buf ^= 1;
  }

  if (MODE == 0) {
    const int cr = hi * 4;
    #pragma unroll
    for (int m = 0; m < MR; ++m)
      #pragma unroll
      for (int n = 0; n < NR; ++n) {
        int col = n0 + wc * (BN / 2) + n * 16 + lo;
        int rowb = m0 + wr * (BM / 2) + m * 16 + cr;
        #pragma unroll
        for (int r = 0; r < 4; ++r)
          C[(size_t)(rowb + r) * N + col] = acc[m][n][r];
      }
  } else {
    const int col0 = n0 + wc * (BN / 2);
    const int pos = posp[0];
    const float qsc = 0.125f * 1.44269504f;   // 1/sqrt(HD) * log2(e)
    if (col0 < 2048) {            // ---- Q + RoPE, pre-scaled ----
      const int h = col0 >> 6;
      #pragma unroll
      for (int m = 0; m < MR; ++m)
        #pragma unroll
        for (int r = 0; r < 4; ++r) {
          int row = m0 + wr * (BM / 2) + m * 16 + hi * 4 + r;
          int s = row & (S_ - 1), b = row >> 10;
          unsigned short* base = q_r + ((size_t)(b * H_ + h) * S_ + s) * HD_;
          #pragma unroll
          for (int np = 0; np < 2; ++np) {
            int i = np * 16 + lo;
            float t1 = acc[m][np][r], t2 = acc[m][np + 2][r];
            float c = cosT[(size_t)(pos + s) * 32 + i];
            float sn = sinT[(size_t)(pos + s) * 32 + i];
            base[i] = f2bf((t1 * c - t2 * sn) * qsc);
            base[i + 32] = f2bf((t2 * c + t1 * sn) * qsc);
          }
        }
    } else if (col0 < 2304) {     // ---- K + RoPE ----
      const int g = (col0 - 2048) >> 6;
      #pragma unroll
      for (int m = 0; m < MR; ++m)
        #pragma unroll
        for (int r = 0; r < 4; ++r) {
          int row = m0 + wr * (BM / 2) + m * 16 + hi * 4 + r;
          int s = row & (S_ - 1), b = row >> 10;
          unsigned short* base = k_r + ((size_t)(b * KV_ + g) * S_ + s) * HD_;
          #pragma unroll
          for (int np = 0; np < 2; ++np) {
            int i = np * 16 + lo;
            float t1 = acc[m][np][r], t2 = acc[m][np + 2][r];
            float c = cosT[(size_t)(pos + s) * 32 + i];
            float sn = sinT[(size_t)(pos + s) * 32 + i];
            base[i] = f2bf(t1 * c - t2 * sn);
            base[i + 32] = f2bf(t2 * c + t1 * sn);
          }
        }
    } else {                      // ---- V -> (B,KV,HD,S) transposed bf16 ----
      const int g = (col0 - 2304) >> 6;
      #pragma unroll
      for (int m = 0; m < MR; ++m) {
        int row0 = m0 + wr * (BM / 2) + m * 16 + hi * 4;
        int s0 = row0 & (S_ - 1), b = row0 >> 10;
        #pragma unroll
        for (int n = 0; n < NR; ++n) {
          int d = n * 16 + lo;
          ushort4 o;
          o.x = f2bf(acc[m][n][0]);
          o.y = f2bf(acc[m][n][1]);
          o.z = f2bf(acc[m][n][2]);
          o.w = f2bf(acc[m][n][3]);
          *(ushort4*)(v_t + ((size_t)(b * KV_ + g) * HD_ + d) * S_ + s0) = o;
        }
      }
    }
  }
}

// ---------------- MFMA flash attention, 32x32 swapped-QK^T, log2-domain softmax ------------
// grid (64 bh, 16 qt); heavy-first (qt = 15 - blockIdx.y). 2 waves x 32 q = 64 q/block.
// (R13 version — paired-chunk variant regressed, reverted.)
__global__ __launch_bounds__(128) void k_attn(const unsigned short* __restrict__ qr,
                                              const unsigned short* __restrict__ kr,
                                              const unsigned short* __restrict__ vt,
                                              unsigned short* __restrict__ ao) {
  __shared__ alignas(16) unsigned short k_lds[2 * KVB * HD_];   // [buf][j][d], chunk-XOR-swz
  __shared__ alignas(16) unsigned short v_lds[2 * HD_ * KVB];   // [buf][d][j], chunk-XOR-swz
  const int tid = threadIdx.x;
  const int wid = tid >> 6, lane = tid & 63;
  const int l31 = lane & 31, hi5 = lane >> 5;
  const int bh = blockIdx.x;
  const int h = bh >> 1, b = bh & 1, g = h >> 3;
  const int qt = 15 - (int)blockIdx.y;            // heavy-first dispatch
  const int nch = qt + 1;
  const int q_abs = qt * 64 + wid * 32 + l31;

  const unsigned short* qrow = qr + ((size_t)(b * H_ + h) * S_ + q_abs) * HD_;
  bf16x8 qf[4];
  #pragma unroll
  for (int ks = 0; ks < 4; ++ks)
    qf[ks] = *(const bf16x8*)(qrow + ks * 16 + hi5 * 8);

  const unsigned short* kbase = kr + (size_t)(b * KV_ + g) * S_ * HD_;
  const unsigned short* vbase = vt + (size_t)(b * KV_ + g) * HD_ * S_;

  const unsigned short* kg[4];
  const unsigned short* vg[4];
  int ldo[4];
  #pragma unroll
  for (int ii = 0; ii < 4; ++ii) {
    int uu = ii * 128 + tid;               // 16B unit, 0..511
    int r = uu >> 3, ch = uu & 7, chs = ch ^ (r & 7);
    kg[ii] = kbase + r * HD_ + chs * 8;
    vg[ii] = vbase + (size_t)r * S_ + chs * 8;
    ldo[ii] = uu * 8;
  }
  int chs8[4];
  #pragma unroll
  for (int ks = 0; ks < 4; ++ks) chs8[ks] = ((ks * 2 + hi5) ^ (l31 & 7)) * 8;
  const int krow = l31 * 64;

  f32x16 oacc[2] = {};   // O^T: col q=l31, row d=(r&3)+8*(r>>2)+4*hi5+32*dt
  float mrun = -1e30f, ls = 0.f;
  int buf = 0;

  auto stage = [&](int c, int bi) {
    #pragma unroll
    for (int ii = 0; ii < 4; ++ii)
      GLOAD_LDS(kg[ii] + (size_t)c * (KVB * HD_), k_lds + bi * 4096 + ldo[ii]);
    #pragma unroll
    for (int ii = 0; ii < 4; ++ii)
      GLOAD_LDS(vg[ii] + (size_t)c * KVB, v_lds + bi * 4096 + ldo[ii]);
  };

  stage(0, 0);
  __syncthreads();

  for (int c = 0; c < nch; ++c) {
    if (c + 1 < nch) stage(c + 1, buf ^ 1);
    const unsigned short* kl = k_lds + buf * 4096;
    const unsigned short* vl = v_lds + buf * 4096;
    const int j0 = c * KVB;

    // S^T tiles (32j x 32q): A = K rows, B = Q
    f32x16 st[2] = {};
    __builtin_amdgcn_s_setprio(1);
    #pragma unroll
    for (int ks = 0; ks < 4; ++ks)
      #pragma unroll
      for (int jt = 0; jt < 2; ++jt) {
        bf16x8 kf = *(const bf16x8*)(kl + jt * 2048 + krow + chs8[ks]);
        st[jt] = __builtin_amdgcn_mfma_f32_32x32x16_bf16(kf, qf[ks], st[jt], 0, 0, 0);
      }
    __builtin_amdgcn_s_setprio(0);

    // causal mask (diagonal chunk only) + row max
    float pmax = -1e30f;
    if (c == nch - 1) {
      #pragma unroll
      for (int jt = 0; jt < 2; ++jt)
        #pragma unroll
        for (int r = 0; r < 16; ++r) {
          int j_abs = j0 + jt * 32 + (r & 3) + 8 * (r >> 2) + 4 * hi5;
          if (j_abs > q_abs) st[jt][r] = -1e30f;
          pmax = fmaxf(pmax, st[jt][r]);
        }
    } else {
      #pragma unroll
      for (int jt = 0; jt < 2; ++jt)
        #pragma unroll
        for (int r = 0; r < 16; ++r) pmax = fmaxf(pmax, st[jt][r]);
    }
    pmax = fmaxf(pmax, __shfl_xor(pmax, 32, 64));   // lane pair shares q

    // defer-max: rescale only when some lane's max rose (wave-uniform branch)
    if (__any(pmax > mrun)) {
      float mn = fmaxf(mrun, pmax);
      float scale = exp2f_fast(mrun - mn);
      ls *= scale;
      #pragma unroll
      for (int dt = 0; dt < 2; ++dt)
        #pragma unroll
        for (int r = 0; r < 16; ++r) oacc[dt][r] *= scale;
      mrun = mn;
    }
    float ls0 = 0.f, ls1 = 0.f, ls2 = 0.f, ls3 = 0.f;
    #pragma unroll
    for (int jt = 0; jt < 2; ++jt)
      #pragma unroll
      for (int r = 0; r < 16; ++r) {
        float e = exp2f_fast(st[jt][r] - mrun);   // log2-domain: bare v_exp_f32
        st[jt][r] = e;
        if ((r & 3) == 0) ls0 += e; else if ((r & 3) == 1) ls1 += e;
        else if ((r & 3) == 2) ls2 += e; else ls3 += e;
      }
    ls += (ls0 + ls1) + (ls2 + ls3);

    // pack P to bf16 quads via v_cvt_pk_bf16_f32 (pk[jt][quad] = rows {4q..4q+3})
    unsigned int pk[2][4][2];
    #pragma unroll
    for (int jt = 0; jt < 2; ++jt)
      #pragma unroll
      for (int qd = 0; qd < 4; ++qd) {
        pk[jt][qd][0] = cvt_pk_bf16(st[jt][qd * 4 + 0], st[jt][qd * 4 + 1]);
        pk[jt][qd][1] = cvt_pk_bf16(st[jt][qd * 4 + 2], st[jt][qd * 4 + 3]);
      }

    // redistribute across lane^32 into PV B-fragments (k=j, col=q)
    bf16x8 pf[4];
    #pragma unroll
    for (int jt = 0; jt < 2; ++jt) {
      unsigned int ex0a = hi5 ? pk[jt][0][0] : pk[jt][1][0];
      unsigned int ex0b = hi5 ? pk[jt][0][1] : pk[jt][1][1];
      unsigned int ex1a = hi5 ? pk[jt][2][0] : pk[jt][3][0];
      unsigned int ex1b = hi5 ? pk[jt][2][1] : pk[jt][3][1];
      unsigned int rA0 = (unsigned int)__shfl_xor((int)ex0a, 32, 64);
      unsigned int rA1 = (unsigned int)__shfl_xor((int)ex0b, 32, 64);
      unsigned int rB0 = (unsigned int)__shfl_xor((int)ex1a, 32, 64);
      unsigned int rB1 = (unsigned int)__shfl_xor((int)ex1b, 32, 64);
      union { unsigned int w[4]; bf16x8 v; } fe, fo;
      if (hi5) {
        fe.w[0] = rA0; fe.w[1] = rA1; fe.w[2] = pk[jt][1][0]; fe.w[3] = pk[jt][1][1];
        fo.w[0] = rB0; fo.w[1] = rB1; fo.w[2] = pk[jt][3][0]; fo.w[3] = pk[jt][3][1];
      } else {
        fe.w[0] = pk[jt][0][0]; fe.w[1] = pk[jt][0][1]; fe.w[2] = rA0; fe.w[3] = rA1;
        fo.w[0] = pk[jt][2][0]; fo.w[1] = pk[jt][2][1]; fo.w[2] = rB0; fo.w[3] = rB1;
      }
      pf[jt * 2 + 0] = fe.v;
      pf[jt * 2 + 1] = fo.v;
    }

    // O^T += Vt · P^T
    __builtin_amdgcn_s_setprio(1);
    #pragma unroll
    for (int ks = 0; ks < 4; ++ks)
      #pragma unroll
      for (int dt = 0; dt < 2; ++dt) {
        bf16x8 vf = *(const bf16x8*)(vl + dt * 2048 + krow + chs8[ks]);
        oacc[dt] = __builtin_amdgcn_mfma_f32_32x32x16_bf16(vf, pf[ks], oacc[dt], 0, 0, 0);
      }
    __builtin_amdgcn_s_setprio(0);

    __syncthreads();   // prefetch landed; all waves done with buf
    buf ^= 1;
  }

  float tot = ls + __shfl_xor(ls, 32, 64);
  float inv = 1.f / tot;
  unsigned short* orow = ao + (size_t)(b * S_ + q_abs) * (H_ * HD_) + h * HD_;
  #pragma unroll
  for (int dt = 0; dt < 2; ++dt)
    #pragma unroll
    for (int rg = 0; rg < 4; ++rg) {
      uint2 w;
      w.x = cvt_pk_bf16(oacc[dt][rg * 4 + 0] * inv, oacc[dt][rg * 4 + 1] * inv);
      w.y = cvt_pk_bf16(oacc[dt][rg * 4 + 2] * inv, oacc[dt][rg * 4 + 3] * inv);
      *(uint2*)(orow + dt * 32 + rg * 8 + hi5 * 4) = w;
    }
}

extern "C" void kernel_launch(void* const* d_in, const int* in_sizes, int n_in,
                              void* d_out, int out_size, void* d_ws, size_t ws_size,
                              hipStream_t stream) {
  const float* x    = (const float*)d_in[0];
  const float* wq   = (const float*)d_in[1];
  const float* wk   = (const float*)d_in[2];
  const float* wv   = (const float*)d_in[3];
  const float* wo   = (const float*)d_in[4];
  const float* cosT = (const float*)d_in[5];
  const float* sinT = (const float*)d_in[6];
  const int*   posp = (const int*)d_in[8];
  float* out = (float*)d_out;

  char* ws = (char*)d_ws;
  size_t off = 0;
  auto alloc = [&](size_t bytes) {
    char* p = ws + off;
    off += (bytes + 255) & ~(size_t)255;
    return p;
  };
  unsigned short* xb  = (unsigned short*)alloc((size_t)B_ * S_ * D_ * 2);
  unsigned short* wft = (unsigned short*)alloc((size_t)NQKV * D_ * 2);
  unsigned short* wot = (unsigned short*)alloc((size_t)D_ * D_ * 2);
  unsigned short* q_r = (unsigned short*)alloc((size_t)B_ * H_ * S_ * HD_ * 2);
  unsigned short* k_r = (unsigned short*)alloc((size_t)B_ * KV_ * S_ * HD_ * 2);
  unsigned short* v_t = (unsigned short*)alloc((size_t)B_ * KV_ * HD_ * S_ * 2);
  unsigned short* ao  = (unsigned short*)alloc((size_t)B_ * S_ * H_ * HD_ * 2);
  if (off > ws_size) return;

  k_convert<<<(B_ * S_ * D_ / 4 + 255) / 256, 256, 0, stream>>>(x, xb, B_ * S_ * D_ / 4);
  k_transpose4<<<dim3(D_ / 32, D_ / 32, 4), 256, 0, stream>>>(wq, wk, wv, wo, wft, wot);

  // QKV GEMM: 128x128 dbuf tiles (320 blocks) with fused RoPE / V-transpose epilogue
  k_gemm<128, 128, 1><<<dim3(NQKV / 128, (B_ * S_) / 128), 256, 0, stream>>>(
      xb, wft, nullptr, cosT, sinT, posp, q_r, k_r, v_t, B_ * S_, NQKV, D_);

  // 32x32 swapped-QK^T attention, heavy-first uniform blocks (2 waves, 64 q each)
  k_attn<<<dim3(64, 16), 128, 0, stream>>>(q_r, k_r, v_t, ao);

  // Output GEMM: 128x128 dbuf tiles (256 blocks)
  k_gemm<128, 128, 0><<<dim3(D_ / 128, (B_ * S_) / 128), 256, 0, stream>>>(
      ao, wot, out, nullptr, nullptr, nullptr, nullptr, nullptr, nullptr, B_ * S_, D_, D_);
}

// Round 19
// 103.527 us; speedup vs baseline: 1.2057x; 1.2018x over previous
//
#include <hip/hip_runtime.h>

#define B_ 2
#define S_ 1024
#define D_ 2048
#define H_ 32
#define KV_ 4
#define HD_ 64
#define NQKV 2560  // H*HD + KV*HD + KV*HD
#define KVB 64     // attention KV chunk

typedef __attribute__((ext_vector_type(8))) short bf16x8;
typedef __attribute__((ext_vector_type(4))) float f32x4;
typedef __attribute__((ext_vector_type(16))) float f32x16;

__device__ __forceinline__ unsigned short f2bf(float f) {
  unsigned int u = __float_as_uint(f);
  u = (u + 0x7fffu + ((u >> 16) & 1u)) >> 16;   // RNE
  return (unsigned short)u;
}
__device__ __forceinline__ unsigned int cvt_pk_bf16(float a, float b) {
  unsigned int r;
  asm("v_cvt_pk_bf16_f32 %0, %1, %2" : "=v"(r) : "v"(a), "v"(b));
  return r;
}
__device__ __forceinline__ float exp2f_fast(float x) {
  return __builtin_amdgcn_exp2f(x);   // bare v_exp_f32
}

#define GLOAD_LDS(gp, lp) \
  __builtin_amdgcn_global_load_lds((const __attribute__((address_space(1))) void*)(gp), \
                                   (__attribute__((address_space(3))) void*)(lp), 16, 0, 0)

// ---------------- merged prep: weight transposes (z=0..3) + x f32->bf16 convert (z=4) -----
__global__ __launch_bounds__(256) void k_prep(const float* __restrict__ x,
                                              const float* __restrict__ wq,
                                              const float* __restrict__ wk,
                                              const float* __restrict__ wv,
                                              const float* __restrict__ wo,
                                              unsigned short* __restrict__ xb,
                                              unsigned short* __restrict__ wft,
                                              unsigned short* __restrict__ wot) {
  const int z = blockIdx.z;
  if (z == 4) {                      // ---- convert x: 4096 blocks x 256 thr x ushort4 ----
    int i = (blockIdx.y * 64 + blockIdx.x) * 256 + threadIdx.x;
    float4 v = ((const float4*)x)[i];
    ushort4 o;
    o.x = f2bf(v.x); o.y = f2bf(v.y); o.z = f2bf(v.z); o.w = f2bf(v.w);
    ((ushort4*)xb)[i] = o;
    return;
  }
  __shared__ float tile[32][33];
  const float* src;
  unsigned short* dst;
  int N, roff;
  if (z == 0)      { src = wq; dst = wft; N = 2048; roff = 0; }
  else if (z == 1) { src = wk; dst = wft; N = 256;  roff = 2048; }
  else if (z == 2) { src = wv; dst = wft; N = 256;  roff = 2304; }
  else             { src = wo; dst = wot; N = 2048; roff = 0; }
  int n0 = blockIdx.x * 32, k0 = blockIdx.y * 32;
  if (n0 >= N) return;
  int tx = threadIdx.x & 31, ty = threadIdx.x >> 5;
  #pragma unroll
  for (int i = 0; i < 4; ++i)
    tile[ty + 8 * i][tx] = src[(size_t)(k0 + ty + 8 * i) * N + (n0 + tx)];
  __syncthreads();
  #pragma unroll
  for (int i = 0; i < 4; ++i)
    dst[(size_t)(roff + n0 + ty + 8 * i) * D_ + (k0 + tx)] = f2bf(tile[tx][ty + 8 * i]);
}

// ---------------- GEMM: C[M][N] = A[M][K] * Bt[N][K]^T, bf16 in (R13 structure) -----------
// BK=128 (16 chunks/row), 4 waves (2x2), single-buffered LDS, 2-barrier loop.
// Staging-port-bound at ~93 GB/s/CU (measured across 10 structure variants).
// LDS XOR-swizzle: stage chunk chs = ch ^ (row&15); read chunk (ks*4+hi) ^ lo.
// MODE 0: plain f32 C write. MODE 1: fused QKV epilogue (RoPE; q pre-scaled by
// log2(e)/sqrt(HD); V transposed to (B,KV,HD,S)). MODE 1 requires BN/2 == 64.
template <int BM, int BN, int MODE>
__global__ __launch_bounds__(256) void k_gemm(const unsigned short* __restrict__ A,
                                              const unsigned short* __restrict__ Bt,
                                              float* __restrict__ C,
                                              const float* __restrict__ cosT,
                                              const float* __restrict__ sinT,
                                              const int* __restrict__ posp,
                                              unsigned short* __restrict__ q_r,
                                              unsigned short* __restrict__ k_r,
                                              unsigned short* __restrict__ v_t,
                                              int M, int N, int K) {
  constexpr int MR = BM / 32;
  constexpr int NR = BN / 32;
  __shared__ alignas(16) unsigned short As[BM * 128];
  __shared__ alignas(16) unsigned short Bs[BN * 128];
  const int tid = threadIdx.x;
  const int wid = tid >> 6, lane = tid & 63;
  const int lo = lane & 15, hi = lane >> 4;
  const int m0 = blockIdx.y * BM, n0 = blockIdx.x * BN;
  const int wr = wid >> 1, wc = wid & 1;
  f32x4 acc[MR][NR] = {};

  const int nkt = K >> 7;
  for (int kt = 0; kt < nkt; ++kt) {
    __syncthreads();
    #pragma unroll
    for (int u = tid; u < BM * 16; u += 256) {
      int row = u >> 4, ch = u & 15, chs = ch ^ (row & 15);
      GLOAD_LDS(A + (size_t)(m0 + row) * K + kt * 128 + chs * 8, As + u * 8);
    }
    #pragma unroll
    for (int u = tid; u < BN * 16; u += 256) {
      int row = u >> 4, ch = u & 15, chs = ch ^ (row & 15);
      GLOAD_LDS(Bt + (size_t)(n0 + row) * K + kt * 128 + chs * 8, Bs + u * 8);
    }
    __syncthreads();
    #pragma unroll
    for (int ks = 0; ks < 4; ++ks) {
      const int chs = (ks * 4 + hi) ^ lo;
      bf16x8 a[MR], b[NR];
      #pragma unroll
      for (int m = 0; m < MR; ++m) {
        int row = wr * (BM / 2) + m * 16 + lo;
        a[m] = *(const bf16x8*)(As + row * 128 + chs * 8);
      }
      #pragma unroll
      for (int n = 0; n < NR; ++n) {
        int row = wc * (BN / 2) + n * 16 + lo;
        b[n] = *(const bf16x8*)(Bs + row * 128 + chs * 8);
      }
      __builtin_amdgcn_s_setprio(1);
      #pragma unroll
      for (int m = 0; m < MR; ++m)
        #pragma unroll
        for (int n = 0; n < NR; ++n)
          acc[m][n] = __builtin_amdgcn_mfma_f32_16x16x32_bf16(a[m], b[n], acc[m][n], 0, 0, 0);
      __builtin_amdgcn_s_setprio(0);
    }
  }

  if (MODE == 0) {
    const int cr = hi * 4;
    #pragma unroll
    for (int m = 0; m < MR; ++m)
      #pragma unroll
      for (int n = 0; n < NR; ++n) {
        int col = n0 + wc * (BN / 2) + n * 16 + lo;
        int rowb = m0 + wr * (BM / 2) + m * 16 + cr;
        #pragma unroll
        for (int r = 0; r < 4; ++r)
          C[(size_t)(rowb + r) * N + col] = acc[m][n][r];
      }
  } else {
    const int col0 = n0 + wc * (BN / 2);
    const int pos = posp[0];
    const float qsc = 0.125f * 1.44269504f;   // 1/sqrt(HD) * log2(e)
    if (col0 < 2048) {            // ---- Q + RoPE, pre-scaled ----
      const int h = col0 >> 6;
      #pragma unroll
      for (int m = 0; m < MR; ++m)
        #pragma unroll
        for (int r = 0; r < 4; ++r) {
          int row = m0 + wr * (BM / 2) + m * 16 + hi * 4 + r;
          int s = row & (S_ - 1), b = row >> 10;
          unsigned short* base = q_r + ((size_t)(b * H_ + h) * S_ + s) * HD_;
          #pragma unroll
          for (int np = 0; np < 2; ++np) {
            int i = np * 16 + lo;
            float t1 = acc[m][np][r], t2 = acc[m][np + 2][r];
            float c = cosT[(size_t)(pos + s) * 32 + i];
            float sn = sinT[(size_t)(pos + s) * 32 + i];
            base[i] = f2bf((t1 * c - t2 * sn) * qsc);
            base[i + 32] = f2bf((t2 * c + t1 * sn) * qsc);
          }
        }
    } else if (col0 < 2304) {     // ---- K + RoPE ----
      const int g = (col0 - 2048) >> 6;
      #pragma unroll
      for (int m = 0; m < MR; ++m)
        #pragma unroll
        for (int r = 0; r < 4; ++r) {
          int row = m0 + wr * (BM / 2) + m * 16 + hi * 4 + r;
          int s = row & (S_ - 1), b = row >> 10;
          unsigned short* base = k_r + ((size_t)(b * KV_ + g) * S_ + s) * HD_;
          #pragma unroll
          for (int np = 0; np < 2; ++np) {
            int i = np * 16 + lo;
            float t1 = acc[m][np][r], t2 = acc[m][np + 2][r];
            float c = cosT[(size_t)(pos + s) * 32 + i];
            float sn = sinT[(size_t)(pos + s) * 32 + i];
            base[i] = f2bf(t1 * c - t2 * sn);
            base[i + 32] = f2bf(t2 * c + t1 * sn);
          }
        }
    } else {                      // ---- V -> (B,KV,HD,S) transposed bf16 ----
      const int g = (col0 - 2304) >> 6;
      #pragma unroll
      for (int m = 0; m < MR; ++m) {
        int row0 = m0 + wr * (BM / 2) + m * 16 + hi * 4;
        int s0 = row0 & (S_ - 1), b = row0 >> 10;
        #pragma unroll
        for (int n = 0; n < NR; ++n) {
          int d = n * 16 + lo;
          ushort4 o;
          o.x = f2bf(acc[m][n][0]);
          o.y = f2bf(acc[m][n][1]);
          o.z = f2bf(acc[m][n][2]);
          o.w = f2bf(acc[m][n][3]);
          *(ushort4*)(v_t + ((size_t)(b * KV_ + g) * HD_ + d) * S_ + s0) = o;
        }
      }
    }
  }
}

// ---------------- MFMA flash attention, 32x32 swapped-QK^T, log2-domain softmax ------------
// grid (64 bh, 16 qt); heavy-first (qt = 15 - blockIdx.y). 2 waves x 32 q = 64 q/block.
__global__ __launch_bounds__(128) void k_attn(const unsigned short* __restrict__ qr,
                                              const unsigned short* __restrict__ kr,
                                              const unsigned short* __restrict__ vt,
                                              unsigned short* __restrict__ ao) {
  __shared__ alignas(16) unsigned short k_lds[2 * KVB * HD_];   // [buf][j][d], chunk-XOR-swz
  __shared__ alignas(16) unsigned short v_lds[2 * HD_ * KVB];   // [buf][d][j], chunk-XOR-swz
  const int tid = threadIdx.x;
  const int wid = tid >> 6, lane = tid & 63;
  const int l31 = lane & 31, hi5 = lane >> 5;
  const int bh = blockIdx.x;
  const int h = bh >> 1, b = bh & 1, g = h >> 3;
  const int qt = 15 - (int)blockIdx.y;            // heavy-first dispatch
  const int nch = qt + 1;
  const int q_abs = qt * 64 + wid * 32 + l31;

  const unsigned short* qrow = qr + ((size_t)(b * H_ + h) * S_ + q_abs) * HD_;
  bf16x8 qf[4];
  #pragma unroll
  for (int ks = 0; ks < 4; ++ks)
    qf[ks] = *(const bf16x8*)(qrow + ks * 16 + hi5 * 8);

  const unsigned short* kbase = kr + (size_t)(b * KV_ + g) * S_ * HD_;
  const unsigned short* vbase = vt + (size_t)(b * KV_ + g) * HD_ * S_;

  const unsigned short* kg[4];
  const unsigned short* vg[4];
  int ldo[4];
  #pragma unroll
  for (int ii = 0; ii < 4; ++ii) {
    int uu = ii * 128 + tid;               // 16B unit, 0..511
    int r = uu >> 3, ch = uu & 7, chs = ch ^ (r & 7);
    kg[ii] = kbase + r * HD_ + chs * 8;
    vg[ii] = vbase + (size_t)r * S_ + chs * 8;
    ldo[ii] = uu * 8;
  }
  int chs8[4];
  #pragma unroll
  for (int ks = 0; ks < 4; ++ks) chs8[ks] = ((ks * 2 + hi5) ^ (l31 & 7)) * 8;
  const int krow = l31 * 64;

  f32x16 oacc[2] = {};   // O^T: col q=l31, row d=(r&3)+8*(r>>2)+4*hi5+32*dt
  float mrun = -1e30f, ls = 0.f;
  int buf = 0;

  auto stage = [&](int c, int bi) {
    #pragma unroll
    for (int ii = 0; ii < 4; ++ii)
      GLOAD_LDS(kg[ii] + (size_t)c * (KVB * HD_), k_lds + bi * 4096 + ldo[ii]);
    #pragma unroll
    for (int ii = 0; ii < 4; ++ii)
      GLOAD_LDS(vg[ii] + (size_t)c * KVB, v_lds + bi * 4096 + ldo[ii]);
  };

  stage(0, 0);
  __syncthreads();

  for (int c = 0; c < nch; ++c) {
    if (c + 1 < nch) stage(c + 1, buf ^ 1);
    const unsigned short* kl = k_lds + buf * 4096;
    const unsigned short* vl = v_lds + buf * 4096;
    const int j0 = c * KVB;

    // S^T tiles (32j x 32q): A = K rows, B = Q
    f32x16 st[2] = {};
    __builtin_amdgcn_s_setprio(1);
    #pragma unroll
    for (int ks = 0; ks < 4; ++ks)
      #pragma unroll
      for (int jt = 0; jt < 2; ++jt) {
        bf16x8 kf = *(const bf16x8*)(kl + jt * 2048 + krow + chs8[ks]);
        st[jt] = __builtin_amdgcn_mfma_f32_32x32x16_bf16(kf, qf[ks], st[jt], 0, 0, 0);
      }
    __builtin_amdgcn_s_setprio(0);

    // causal mask (diagonal chunk only) + row max
    float pmax = -1e30f;
    if (c == nch - 1) {
      #pragma unroll
      for (int jt = 0; jt < 2; ++jt)
        #pragma unroll
        for (int r = 0; r < 16; ++r) {
          int j_abs = j0 + jt * 32 + (r & 3) + 8 * (r >> 2) + 4 * hi5;
          if (j_abs > q_abs) st[jt][r] = -1e30f;
          pmax = fmaxf(pmax, st[jt][r]);
        }
    } else {
      #pragma unroll
      for (int jt = 0; jt < 2; ++jt)
        #pragma unroll
        for (int r = 0; r < 16; ++r) pmax = fmaxf(pmax, st[jt][r]);
    }
    pmax = fmaxf(pmax, __shfl_xor(pmax, 32, 64));   // lane pair shares q

    // defer-max: rescale only when some lane's max rose (wave-uniform branch)
    if (__any(pmax > mrun)) {
      float mn = fmaxf(mrun, pmax);
      float scale = exp2f_fast(mrun - mn);
      ls *= scale;
      #pragma unroll
      for (int dt = 0; dt < 2; ++dt)
        #pragma unroll
        for (int r = 0; r < 16; ++r) oacc[dt][r] *= scale;
      mrun = mn;
    }
    float ls0 = 0.f, ls1 = 0.f, ls2 = 0.f, ls3 = 0.f;
    #pragma unroll
    for (int jt = 0; jt < 2; ++jt)
      #pragma unroll
      for (int r = 0; r < 16; ++r) {
        float e = exp2f_fast(st[jt][r] - mrun);   // log2-domain: bare v_exp_f32
        st[jt][r] = e;
        if ((r & 3) == 0) ls0 += e; else if ((r & 3) == 1) ls1 += e;
        else if ((r & 3) == 2) ls2 += e; else ls3 += e;
      }
    ls += (ls0 + ls1) + (ls2 + ls3);

    // pack P to bf16 quads via v_cvt_pk_bf16_f32 (pk[jt][quad] = rows {4q..4q+3})
    unsigned int pk[2][4][2];
    #pragma unroll
    for (int jt = 0; jt < 2; ++jt)
      #pragma unroll
      for (int qd = 0; qd < 4; ++qd) {
        pk[jt][qd][0] = cvt_pk_bf16(st[jt][qd * 4 + 0], st[jt][qd * 4 + 1]);
        pk[jt][qd][1] = cvt_pk_bf16(st[jt][qd * 4 + 2], st[jt][qd * 4 + 3]);
      }

    // redistribute across lane^32 into PV B-fragments (k=j, col=q)
    bf16x8 pf[4];
    #pragma unroll
    for (int jt = 0; jt < 2; ++jt) {
      unsigned int ex0a = hi5 ? pk[jt][0][0] : pk[jt][1][0];
      unsigned int ex0b = hi5 ? pk[jt][0][1] : pk[jt][1][1];
      unsigned int ex1a = hi5 ? pk[jt][2][0] : pk[jt][3][0];
      unsigned int ex1b = hi5 ? pk[jt][2][1] : pk[jt][3][1];
      unsigned int rA0 = (unsigned int)__shfl_xor((int)ex0a, 32, 64);
      unsigned int rA1 = (unsigned int)__shfl_xor((int)ex0b, 32, 64);
      unsigned int rB0 = (unsigned int)__shfl_xor((int)ex1a, 32, 64);
      unsigned int rB1 = (unsigned int)__shfl_xor((int)ex1b, 32, 64);
      union { unsigned int w[4]; bf16x8 v; } fe, fo;
      if (hi5) {
        fe.w[0] = rA0; fe.w[1] = rA1; fe.w[2] = pk[jt][1][0]; fe.w[3] = pk[jt][1][1];
        fo.w[0] = rB0; fo.w[1] = rB1; fo.w[2] = pk[jt][3][0]; fo.w[3] = pk[jt][3][1];
      } else {
        fe.w[0] = pk[jt][0][0]; fe.w[1] = pk[jt][0][1]; fe.w[2] = rA0; fe.w[3] = rA1;
        fo.w[0] = pk[jt][2][0]; fo.w[1] = pk[jt][2][1]; fo.w[2] = rB0; fo.w[3] = rB1;
      }
      pf[jt * 2 + 0] = fe.v;
      pf[jt * 2 + 1] = fo.v;
    }

    // O^T += Vt · P^T
    __builtin_amdgcn_s_setprio(1);
    #pragma unroll
    for (int ks = 0; ks < 4; ++ks)
      #pragma unroll
      for (int dt = 0; dt < 2; ++dt) {
        bf16x8 vf = *(const bf16x8*)(vl + dt * 2048 + krow + chs8[ks]);
        oacc[dt] = __builtin_amdgcn_mfma_f32_32x32x16_bf16(vf, pf[ks], oacc[dt], 0, 0, 0);
      }
    __builtin_amdgcn_s_setprio(0);

    __syncthreads();   // prefetch landed; all waves done with buf
    buf ^= 1;
  }

  float tot = ls + __shfl_xor(ls, 32, 64);
  float inv = 1.f / tot;
  unsigned short* orow = ao + (size_t)(b * S_ + q_abs) * (H_ * HD_) + h * HD_;
  #pragma unroll
  for (int dt = 0; dt < 2; ++dt)
    #pragma unroll
    for (int rg = 0; rg < 4; ++rg) {
      uint2 w;
      w.x = cvt_pk_bf16(oacc[dt][rg * 4 + 0] * inv, oacc[dt][rg * 4 + 1] * inv);
      w.y = cvt_pk_bf16(oacc[dt][rg * 4 + 2] * inv, oacc[dt][rg * 4 + 3] * inv);
      *(uint2*)(orow + dt * 32 + rg * 8 + hi5 * 4) = w;
    }
}

extern "C" void kernel_launch(void* const* d_in, const int* in_sizes, int n_in,
                              void* d_out, int out_size, void* d_ws, size_t ws_size,
                              hipStream_t stream) {
  const float* x    = (const float*)d_in[0];
  const float* wq   = (const float*)d_in[1];
  const float* wk   = (const float*)d_in[2];
  const float* wv   = (const float*)d_in[3];
  const float* wo   = (const float*)d_in[4];
  const float* cosT = (const float*)d_in[5];
  const float* sinT = (const float*)d_in[6];
  const int*   posp = (const int*)d_in[8];
  float* out = (float*)d_out;

  char* ws = (char*)d_ws;
  size_t off = 0;
  auto alloc = [&](size_t bytes) {
    char* p = ws + off;
    off += (bytes + 255) & ~(size_t)255;
    return p;
  };
  unsigned short* xb  = (unsigned short*)alloc((size_t)B_ * S_ * D_ * 2);
  unsigned short* wft = (unsigned short*)alloc((size_t)NQKV * D_ * 2);
  unsigned short* wot = (unsigned short*)alloc((size_t)D_ * D_ * 2);
  unsigned short* q_r = (unsigned short*)alloc((size_t)B_ * H_ * S_ * HD_ * 2);
  unsigned short* k_r = (unsigned short*)alloc((size_t)B_ * KV_ * S_ * HD_ * 2);
  unsigned short* v_t = (unsigned short*)alloc((size_t)B_ * KV_ * HD_ * S_ * 2);
  unsigned short* ao  = (unsigned short*)alloc((size_t)B_ * S_ * H_ * HD_ * 2);
  if (off > ws_size) return;

  // merged prep: 4 weight transposes + x convert in one launch
  k_prep<<<dim3(64, 64, 5), 256, 0, stream>>>(x, wq, wk, wv, wo, xb, wft, wot);

  // QKV GEMM (BK=128, single-buf 2-barrier) with fused RoPE / V-transpose epilogue
  k_gemm<64, 128, 1><<<dim3(NQKV / 128, (B_ * S_) / 64), 256, 0, stream>>>(
      xb, wft, nullptr, cosT, sinT, posp, q_r, k_r, v_t, B_ * S_, NQKV, D_);

  // 32x32 swapped-QK^T attention, heavy-first uniform blocks (2 waves, 64 q each)
  k_attn<<<dim3(64, 16), 128, 0, stream>>>(q_r, k_r, v_t, ao);

  // Output GEMM (BK=128, single-buf 2-barrier), 64x128 tiles
  k_gemm<64, 128, 0><<<dim3(D_ / 128, (B_ * S_) / 64), 256, 0, stream>>>(
      ao, wot, out, nullptr, nullptr, nullptr, nullptr, nullptr, nullptr, B_ * S_, D_, D_);
}